// Round 7
// baseline (705.191 us; speedup 1.0000x reference)
//
#include <hip/hip_runtime.h>
#include <hip/hip_bf16.h>
#include <math.h>

#define NN    32768      // nodes
#define FIN   128        // input features
#define DD    512        // hidden dim
#define NDOCS 256        // documents
#define NE    262144     // edges
#define NPD   128        // nodes per doc

typedef __attribute__((ext_vector_type(8))) short s16x8;
typedef __attribute__((ext_vector_type(4))) float f32x4;

__device__ __forceinline__ unsigned short f2bf(float f) {
    union { float f; unsigned int u; } v; v.f = f;
    unsigned int r = (v.u + 0x7FFFu + ((v.u >> 16) & 1u)) >> 16;
    return (unsigned short)r;
}
__device__ __forceinline__ float bf2f(unsigned int h) {
    union { unsigned int u; float f; } v; v.u = h << 16;
    return v.f;
}

__device__ __forceinline__ void gl2lds16(const void* g, void* l) {
    __builtin_amdgcn_global_load_lds(
        (const __attribute__((address_space(1))) int*)g,
        (__attribute__((address_space(3))) int*)l, 16, 0, 0);
}

// ---------------------------------------------------------------------------
// graph structure build. Packed edge u32: low16 = src id, high16 = bf16(norm).
// Each node's CSR row is [self-edge, incoming edges...]; self weight = 1/deg.
// ---------------------------------------------------------------------------
__global__ __launch_bounds__(256) void init_deg(int* __restrict__ deg) {
    int i = blockIdx.x * 256 + threadIdx.x;
    if (i < NN) deg[i] = 1;
}

__global__ __launch_bounds__(256) void count_deg(const int* __restrict__ dst, int* __restrict__ deg) {
    int e = blockIdx.x * 256 + threadIdx.x;
    if (e < NE) atomicAdd(&deg[dst[e]], 1);
}

__global__ __launch_bounds__(1024) void scan_kernel(const int* __restrict__ deg, float* __restrict__ dis,
                                                    int* __restrict__ row_ptr, int* __restrict__ cursor,
                                                    unsigned int* __restrict__ csr_pack) {
    __shared__ int part[1024];
    int t = threadIdx.x;
    const int CH = NN / 1024;   // 32
    int base = t * CH;
    int sum = 0;
    for (int i = 0; i < CH; ++i) {
        int d = deg[base + i];
        dis[base + i] = rsqrtf((float)d);
        sum += d;               // self + in-degree
    }
    part[t] = sum;
    __syncthreads();
    for (int off = 1; off < 1024; off <<= 1) {
        int v = (t >= off) ? part[t - off] : 0;
        __syncthreads();
        part[t] += v;
        __syncthreads();
    }
    int excl = (t == 0) ? 0 : part[t - 1];
    for (int i = 0; i < CH; ++i) {
        int node = base + i;
        int d = deg[node];
        row_ptr[node] = excl;
        // self edge: weight = dis^2 = 1/deg exactly
        csr_pack[excl] = ((unsigned int)f2bf(1.0f / (float)d) << 16) | (unsigned int)node;
        cursor[node] = excl + 1;
        excl += d;
    }
    if (t == 1023) row_ptr[NN] = part[1023];
}

__global__ __launch_bounds__(256) void fill_csr(const int* __restrict__ src, const int* __restrict__ dst,
                                                const float* __restrict__ dis,
                                                int* __restrict__ cursor, unsigned int* __restrict__ csr_pack) {
    int e = blockIdx.x * 256 + threadIdx.x;
    if (e < NE) {
        int d = dst[e];
        int s = src[e];
        int pos = atomicAdd(&cursor[d], 1);
        csr_pack[pos] = ((unsigned int)f2bf(dis[s] * dis[d]) << 16) | (unsigned int)s;
    }
}

__global__ __launch_bounds__(128) void doc_attn(const float* __restrict__ attn, float* __restrict__ dm) {
    int d = blockIdx.x;
    int t = threadIdx.x;
    float v = attn[d * NPD + t];
    #pragma unroll
    for (int off = 32; off >= 1; off >>= 1) v += __shfl_down(v, off);
    __shared__ float sm[2];
    if ((t & 63) == 0) sm[t >> 6] = v;
    __syncthreads();
    if (t == 0) dm[d] = (sm[0] + sm[1]) * (1.0f / (float)NPD);
}

// ---------------------------------------------------------------------------
// conversions
// ---------------------------------------------------------------------------
__global__ __launch_bounds__(256) void cvt_x(const float* __restrict__ x, unsigned short* __restrict__ xb) {
    int i = blockIdx.x * 256 + threadIdx.x;   // per 4 elements
    float4 v = ((const float4*)x)[i];
    ushort4 o;
    o.x = f2bf(v.x); o.y = f2bf(v.y); o.z = f2bf(v.z); o.w = f2bf(v.w);
    ((ushort4*)xb)[i] = o;
}

// all weight transposes+casts in one kernel (grid = 868352/256 = 3392)
__global__ __launch_bounds__(256) void cvt_all(const float* __restrict__ Wi, const float* __restrict__ Wh,
                                               const float* __restrict__ Wo, const float* __restrict__ Wf1,
                                               const float* __restrict__ Wf2,
                                               unsigned short* __restrict__ Ti, unsigned short* __restrict__ Th,
                                               unsigned short* __restrict__ To, unsigned short* __restrict__ Tf1,
                                               unsigned short* __restrict__ Tf2) {
    int idx = blockIdx.x * 256 + threadIdx.x;
    if (idx < 65536) {                      // W_in [128 x 512]
        int k = idx >> 9, n = idx & 511;
        Ti[(size_t)n * FIN + k] = f2bf(Wi[idx]);
        return;
    }
    idx -= 65536;
    if (idx < 262144) {                     // W_hid [512 x 512]
        int k = idx >> 9, n = idx & 511;
        Th[(size_t)n * DD + k] = f2bf(Wh[idx]);
        return;
    }
    idx -= 262144;
    if (idx < 262144) {                     // W_out
        int k = idx >> 9, n = idx & 511;
        To[(size_t)n * DD + k] = f2bf(Wo[idx]);
        return;
    }
    idx -= 262144;
    if (idx < 262144) {                     // W_fc1
        int k = idx >> 9, n = idx & 511;
        Tf1[(size_t)n * DD + k] = f2bf(Wf1[idx]);
        return;
    }
    idx -= 262144;
    if (idx < 16384) {                      // W_fc2 [512 x 32]
        int k = idx >> 5, n = idx & 31;
        Tf2[(size_t)n * DD + k] = f2bf(Wf2[idx]);
    }
}

// ---------------------------------------------------------------------------
// LDS-free MFMA bf16 GEMM: C[MxN] = A[MxK] @ Bt[NxK]^T.
// One wave per 64x64 output tile; A/B fragments read directly global->VGPR
// (B is L2-resident weights; A reuse served by L2/L3). No barriers, no LDS,
// no bank conflicts; waves free-run with 8 indep loads per unrolled step.
// ---------------------------------------------------------------------------
template<int K, bool FUSE>
__global__ __launch_bounds__(256) void gemm_nolds(const unsigned short* __restrict__ A,
                                                  const unsigned short* __restrict__ Bt,
                                                  const float* __restrict__ bias,
                                                  unsigned short* __restrict__ C,
                                                  int N) {
    int tid  = threadIdx.x;
    int lane = tid & 63;
    int wave = tid >> 6;
    int m0 = blockIdx.y * 128 + (wave >> 1) * 64;
    int n0 = blockIdx.x * 128 + (wave & 1) * 64;

    f32x4 zero = {0.f, 0.f, 0.f, 0.f};
    f32x4 acc[4][4];
    #pragma unroll
    for (int mi = 0; mi < 4; ++mi)
        #pragma unroll
        for (int ni = 0; ni < 4; ++ni) acc[mi][ni] = zero;

    // fragment base: row = tile_base + (lane&15), k-offset = (lane>>4)*8
    const unsigned short* abase = A  + (size_t)(m0 + (lane & 15)) * K + (lane >> 4) * 8;
    const unsigned short* bbase = Bt + (size_t)(n0 + (lane & 15)) * K + (lane >> 4) * 8;

    #pragma unroll 4
    for (int ks = 0; ks < K / 32; ++ks) {
        int kk = ks * 32;
        s16x8 af[4], bfr[4];
        #pragma unroll
        for (int mi = 0; mi < 4; ++mi)
            af[mi] = *(const s16x8*)(abase + (size_t)mi * 16 * K + kk);
        #pragma unroll
        for (int ni = 0; ni < 4; ++ni)
            bfr[ni] = *(const s16x8*)(bbase + (size_t)ni * 16 * K + kk);
        #pragma unroll
        for (int mi = 0; mi < 4; ++mi)
            #pragma unroll
            for (int ni = 0; ni < 4; ++ni)
                acc[mi][ni] = __builtin_amdgcn_mfma_f32_16x16x32_bf16(af[mi], bfr[ni], acc[mi][ni], 0, 0, 0);
    }

    // epilogue: C/D layout col = lane&15, row = (lane>>4)*4 + reg
    int col = lane & 15;
    int rb  = (lane >> 4) * 4;
    #pragma unroll
    for (int ni = 0; ni < 4; ++ni) {
        int n = n0 + ni * 16 + col;
        float bv = 0.f;
        if (FUSE) bv = bias[n];
        #pragma unroll
        for (int mi = 0; mi < 4; ++mi) {
            size_t base = (size_t)(m0 + mi * 16 + rb) * N + n;
            #pragma unroll
            for (int r = 0; r < 4; ++r) {
                float v = acc[mi][ni][r];
                if (FUSE) v = tanhf(v + bv);
                C[base + (size_t)r * N] = f2bf(v);
            }
        }
    }
}

// ---------------------------------------------------------------------------
// 512-wide aggregation (R5 winner): one wave per node, lane = 8 cols (16 B
// coalesced row-gathers), uniform edge loop (self-edge in CSR), clamped
// 4-deep prefetch. out[n] = tanh(sum_e w_e * hw[src_e] + b)
// ---------------------------------------------------------------------------
__global__ __launch_bounds__(256) void agg512(const unsigned short* __restrict__ hw,
                                              const int* __restrict__ row_ptr,
                                              const unsigned int* __restrict__ csr_pack,
                                              const float* __restrict__ bias,
                                              unsigned short* __restrict__ out) {
    int n = blockIdx.x * 4 + (threadIdx.x >> 6);
    int lane = threadIdx.x & 63;
    int cb = lane * 8;
    const unsigned short* tab = hw + cb;
    float acc[8] = {};
    int beg = row_ptr[n], end = row_ptr[n + 1];
    for (int e = beg; e < end; e += 4) {
        int e1 = (e + 1 < end) ? e + 1 : e;
        int e2 = (e + 2 < end) ? e + 2 : e;
        int e3 = (e + 3 < end) ? e + 3 : e;
        unsigned int p0 = csr_pack[e];
        unsigned int p1 = csr_pack[e1];
        unsigned int p2 = csr_pack[e2];
        unsigned int p3 = csr_pack[e3];
        s16x8 u0 = *(const s16x8*)(tab + (size_t)(p0 & 0xffffu) * DD);
        s16x8 u1 = *(const s16x8*)(tab + (size_t)(p1 & 0xffffu) * DD);
        s16x8 u2 = *(const s16x8*)(tab + (size_t)(p2 & 0xffffu) * DD);
        s16x8 u3 = *(const s16x8*)(tab + (size_t)(p3 & 0xffffu) * DD);
        float w0 = bf2f(p0 >> 16);
        float w1 = (e + 1 < end) ? bf2f(p1 >> 16) : 0.f;
        float w2 = (e + 2 < end) ? bf2f(p2 >> 16) : 0.f;
        float w3 = (e + 3 < end) ? bf2f(p3 >> 16) : 0.f;
        #pragma unroll
        for (int j = 0; j < 8; ++j) acc[j] += w0 * bf2f((unsigned short)u0[j]);
        #pragma unroll
        for (int j = 0; j < 8; ++j) acc[j] += w1 * bf2f((unsigned short)u1[j]);
        #pragma unroll
        for (int j = 0; j < 8; ++j) acc[j] += w2 * bf2f((unsigned short)u2[j]);
        #pragma unroll
        for (int j = 0; j < 8; ++j) acc[j] += w3 * bf2f((unsigned short)u3[j]);
    }
    s16x8 o;
    #pragma unroll
    for (int j = 0; j < 8; ++j)
        o[j] = (short)f2bf(tanhf(acc[j] + bias[cb + j]));
    *(s16x8*)(out + (size_t)n * DD + cb) = o;
}

// ---------------------------------------------------------------------------
// 128-wide pre-aggregation of x (R5 winner): lane = 2 cols (u32 gathers)
// ---------------------------------------------------------------------------
__global__ __launch_bounds__(256) void agg128(const unsigned short* __restrict__ xb,
                                              const int* __restrict__ row_ptr,
                                              const unsigned int* __restrict__ csr_pack,
                                              unsigned short* __restrict__ xagg) {
    int n = blockIdx.x * 4 + (threadIdx.x >> 6);
    int lane = threadIdx.x & 63;
    int cb = lane * 2;
    const unsigned short* tab = xb + cb;
    float a0 = 0.f, a1 = 0.f;
    int beg = row_ptr[n], end = row_ptr[n + 1];
    for (int e = beg; e < end; e += 4) {
        int e1 = (e + 1 < end) ? e + 1 : e;
        int e2 = (e + 2 < end) ? e + 2 : e;
        int e3 = (e + 3 < end) ? e + 3 : e;
        unsigned int p0 = csr_pack[e];
        unsigned int p1 = csr_pack[e1];
        unsigned int p2 = csr_pack[e2];
        unsigned int p3 = csr_pack[e3];
        unsigned int u0 = *(const unsigned int*)(tab + (size_t)(p0 & 0xffffu) * FIN);
        unsigned int u1 = *(const unsigned int*)(tab + (size_t)(p1 & 0xffffu) * FIN);
        unsigned int u2 = *(const unsigned int*)(tab + (size_t)(p2 & 0xffffu) * FIN);
        unsigned int u3 = *(const unsigned int*)(tab + (size_t)(p3 & 0xffffu) * FIN);
        float w0 = bf2f(p0 >> 16);
        float w1 = (e + 1 < end) ? bf2f(p1 >> 16) : 0.f;
        float w2 = (e + 2 < end) ? bf2f(p2 >> 16) : 0.f;
        float w3 = (e + 3 < end) ? bf2f(p3 >> 16) : 0.f;
        a0 += w0 * bf2f(u0 & 0xffffu); a1 += w0 * bf2f(u0 >> 16);
        a0 += w1 * bf2f(u1 & 0xffffu); a1 += w1 * bf2f(u1 >> 16);
        a0 += w2 * bf2f(u2 & 0xffffu); a1 += w2 * bf2f(u2 >> 16);
        a0 += w3 * bf2f(u3 & 0xffffu); a1 += w3 * bf2f(u3 >> 16);
    }
    unsigned int o = (unsigned int)f2bf(a0) | ((unsigned int)f2bf(a1) << 16);
    *(unsigned int*)(xagg + (size_t)n * FIN + cb) = o;
}

// ---------------------------------------------------------------------------
// fused fc2+fc3+pool: one block per doc (128 nodes), MFMA 128x32, K=512
// ---------------------------------------------------------------------------
__global__ __launch_bounds__(256) void fc23_pool(const unsigned short* __restrict__ H,
                                                 const unsigned short* __restrict__ W2t,
                                                 const float* __restrict__ b2,
                                                 const float* __restrict__ W3,
                                                 const float* __restrict__ b3,
                                                 float* __restrict__ util) {
    __shared__ __align__(16) unsigned short As[128 * 64];
    __shared__ __align__(16) unsigned short Bs[32 * 64];
    __shared__ float red[4];
    int d = blockIdx.x;
    int tid = threadIdx.x;
    int lane = tid & 63;
    int wave = tid >> 6;
    const unsigned short* A = H + (size_t)d * NPD * DD;

    f32x4 zero = {0.f, 0.f, 0.f, 0.f};
    f32x4 acc[2][2];
    #pragma unroll
    for (int mi = 0; mi < 2; ++mi)
        #pragma unroll
        for (int ni = 0; ni < 2; ++ni) acc[mi][ni] = zero;

    int srow = tid >> 3;
    int scol = (tid & 7) * 8;
    for (int k0 = 0; k0 < DD; k0 += 64) {
        __syncthreads();
        #pragma unroll
        for (int i = 0; i < 4; ++i)
            gl2lds16(A + (size_t)(srow + i * 32) * DD + k0 + scol,
                     As + (size_t)(wave * 64 + i * 256) * 8);
        gl2lds16(W2t + (size_t)srow * DD + k0 + scol, Bs + (size_t)(wave * 64) * 8);
        __syncthreads();
        #pragma unroll
        for (int ks = 0; ks < 2; ++ks) {
            int kk = ks * 32 + (lane >> 4) * 8;
            s16x8 af[2], bfr[2];
            #pragma unroll
            for (int mi = 0; mi < 2; ++mi)
                af[mi] = *(const s16x8*)(As + (size_t)(wave * 32 + mi * 16 + (lane & 15)) * 64 + kk);
            #pragma unroll
            for (int ni = 0; ni < 2; ++ni)
                bfr[ni] = *(const s16x8*)(Bs + (size_t)(ni * 16 + (lane & 15)) * 64 + kk);
            #pragma unroll
            for (int mi = 0; mi < 2; ++mi)
                #pragma unroll
                for (int ni = 0; ni < 2; ++ni)
                    acc[mi][ni] = __builtin_amdgcn_mfma_f32_16x16x32_bf16(af[mi], bfr[ni], acc[mi][ni], 0, 0, 0);
        }
    }

    int col = lane & 15;
    float part = 0.f;
    #pragma unroll
    for (int ni = 0; ni < 2; ++ni) {
        int j = ni * 16 + col;
        float b2v = b2[j];
        float w3v = W3[j];
        #pragma unroll
        for (int mi = 0; mi < 2; ++mi)
            #pragma unroll
            for (int r = 0; r < 4; ++r)
                part += tanhf(acc[mi][ni][r] + b2v) * w3v;
    }
    #pragma unroll
    for (int off = 32; off >= 1; off >>= 1) part += __shfl_down(part, off);
    if (lane == 0) red[wave] = part;
    __syncthreads();
    if (tid == 0) util[d] = (red[0] + red[1] + red[2] + red[3]) * (1.0f / (float)NPD) + b3[0];
}

__global__ __launch_bounds__(256) void final_kernel(const float* __restrict__ util, const float* __restrict__ dm,
                                                    const int* __restrict__ ia, const int* __restrict__ ib,
                                                    float* __restrict__ out) {
    int i = threadIdx.x;
    if (i < NDOCS) {
        float diff = util[ib[i]] - util[ia[i]];
        float a = dm[i ^ 1];
        out[i] = 1.0f / (1.0f + expf(-diff * a));
    }
}

// ---------------------------------------------------------------------------
// launch
// ---------------------------------------------------------------------------
extern "C" void kernel_launch(void* const* d_in, const int* in_sizes, int n_in,
                              void* d_out, int out_size, void* d_ws, size_t ws_size,
                              hipStream_t stream) {
    const float* x      = (const float*)d_in[0];
    const int*   ei     = (const int*)d_in[1];
    const int*   e_src  = ei;
    const int*   e_dst  = ei + NE;
    const float* attn   = (const float*)d_in[4];
    const int*   idx_a  = (const int*)d_in[5];
    const int*   idx_b  = (const int*)d_in[6];
    const float* W_in   = (const float*)d_in[7];
    const float* b_in   = (const float*)d_in[8];
    const float* W_hid  = (const float*)d_in[9];
    const float* b_hid  = (const float*)d_in[10];
    const float* W_out  = (const float*)d_in[11];
    const float* b_out  = (const float*)d_in[12];
    const float* W_fc1  = (const float*)d_in[13];
    const float* b_fc1  = (const float*)d_in[14];
    const float* W_fc2  = (const float*)d_in[15];
    const float* b_fc2  = (const float*)d_in[16];
    const float* W_fc3  = (const float*)d_in[17];
    const float* b_fc3  = (const float*)d_in[18];
    float* out = (float*)d_out;

    // workspace carve-up (16B-aligned by construction)
    char* p = (char*)d_ws;
    unsigned short* hw_bf  = (unsigned short*)p; p += (size_t)NN * DD * 2;   // 32 MB (also hosts xagg)
    unsigned short* h_bf   = (unsigned short*)p; p += (size_t)NN * DD * 2;   // 32 MB
    unsigned short* xb     = (unsigned short*)p; p += (size_t)NN * FIN * 2;  // 8 MB
    unsigned short* Wt_in  = (unsigned short*)p; p += (size_t)DD * FIN * 2;
    unsigned short* Wt_hid = (unsigned short*)p; p += (size_t)DD * DD * 2;
    unsigned short* Wt_out = (unsigned short*)p; p += (size_t)DD * DD * 2;
    unsigned short* Wt_fc1 = (unsigned short*)p; p += (size_t)DD * DD * 2;
    unsigned short* W2t    = (unsigned short*)p; p += (size_t)32 * DD * 2;
    int*   degi     = (int*)p;   p += (size_t)NN * 4;
    float* dis      = (float*)p; p += (size_t)NN * 4;
    float* dm       = (float*)p; p += (size_t)NDOCS * 4;
    float* util     = (float*)p; p += (size_t)NDOCS * 4;
    int*   row_ptr  = (int*)p;   p += (size_t)(NN + 1) * 4 + 12;
    int*   cursor   = (int*)p;   p += (size_t)NN * 4;
    unsigned int* csr_pack = (unsigned int*)p;   p += (size_t)(NE + NN) * 4;
    unsigned short* xagg = hw_bf;   // 8 MB, aliases hw_bf (free before layer-1 GEMM writes h_bf)

    // graph structure
    init_deg<<<NN / 256, 256, 0, stream>>>(degi);
    count_deg<<<NE / 256, 256, 0, stream>>>(e_dst, degi);
    scan_kernel<<<1, 1024, 0, stream>>>(degi, dis, row_ptr, cursor, csr_pack);
    fill_csr<<<NE / 256, 256, 0, stream>>>(e_src, e_dst, dis, cursor, csr_pack);
    doc_attn<<<NDOCS, 128, 0, stream>>>(attn, dm);

    // dtype prep
    cvt_x<<<(NN * FIN / 4) / 256, 256, 0, stream>>>(x, xb);
    cvt_all<<<3392, 256, 0, stream>>>(W_in, W_hid, W_out, W_fc1, W_fc2,
                                      Wt_in, Wt_hid, Wt_out, Wt_fc1, W2t);

    dim3 gg(DD / 128, NN / 128);   // (4, 256)

    // layer 1: aggregate x first (A_norm x) @ W_in, fused bias+tanh
    agg128<<<NN / 4, 256, 0, stream>>>(xb, row_ptr, csr_pack, xagg);
    gemm_nolds<FIN, true><<<gg, 256, 0, stream>>>(xagg, Wt_in, b_in, h_bf, DD);
    // layer 2
    gemm_nolds<DD, false><<<gg, 256, 0, stream>>>(h_bf, Wt_hid, nullptr, hw_bf, DD);
    agg512<<<NN / 4, 256, 0, stream>>>(hw_bf, row_ptr, csr_pack, b_hid, h_bf);
    // layer 3
    gemm_nolds<DD, false><<<gg, 256, 0, stream>>>(h_bf, Wt_hid, nullptr, hw_bf, DD);
    agg512<<<NN / 4, 256, 0, stream>>>(hw_bf, row_ptr, csr_pack, b_hid, h_bf);
    // layer 4
    gemm_nolds<DD, false><<<gg, 256, 0, stream>>>(h_bf, Wt_out, nullptr, hw_bf, DD);
    agg512<<<NN / 4, 256, 0, stream>>>(hw_bf, row_ptr, csr_pack, b_out, h_bf);
    // fc1 (fused bias+tanh)
    gemm_nolds<DD, true><<<gg, 256, 0, stream>>>(h_bf, Wt_fc1, b_fc1, hw_bf, DD);
    // fc2+fc3+pool fused
    fc23_pool<<<NDOCS, 256, 0, stream>>>(hw_bf, W2t, b_fc2, W_fc3, b_fc3, util);
    // readout
    final_kernel<<<1, 256, 0, stream>>>(util, dm, idx_a, idx_b, out);
}

// Round 8
// 537.074 us; speedup vs baseline: 1.3130x; 1.3130x over previous
//
#include <hip/hip_runtime.h>
#include <hip/hip_bf16.h>
#include <math.h>

#define NN    32768      // nodes
#define FIN   128        // input features
#define DD    512        // hidden dim
#define NDOCS 256        // documents
#define NE    262144     // edges
#define NPD   128        // nodes per doc

typedef __attribute__((ext_vector_type(8))) short s16x8;
typedef __attribute__((ext_vector_type(4))) float f32x4;

__device__ __forceinline__ unsigned short f2bf(float f) {
    union { float f; unsigned int u; } v; v.f = f;
    unsigned int r = (v.u + 0x7FFFu + ((v.u >> 16) & 1u)) >> 16;
    return (unsigned short)r;
}
__device__ __forceinline__ float bf2f(unsigned int h) {
    union { unsigned int u; float f; } v; v.u = h << 16;
    return v.f;
}

__device__ __forceinline__ void gl2lds16(const void* g, void* l) {
    __builtin_amdgcn_global_load_lds(
        (const __attribute__((address_space(1))) int*)g,
        (__attribute__((address_space(3))) int*)l, 16, 0, 0);
}

// ---------------------------------------------------------------------------
// graph structure build. Packed edge u32: low16 = src id, high16 = bf16(norm).
// Each node's CSR row is [self-edge, incoming edges...]; self weight = 1/deg.
// ---------------------------------------------------------------------------
__global__ __launch_bounds__(256) void init_deg(int* __restrict__ deg) {
    int i = blockIdx.x * 256 + threadIdx.x;
    if (i < NN) deg[i] = 1;
}

__global__ __launch_bounds__(256) void count_deg(const int* __restrict__ dst, int* __restrict__ deg) {
    int e = blockIdx.x * 256 + threadIdx.x;
    if (e < NE) atomicAdd(&deg[dst[e]], 1);
}

__global__ __launch_bounds__(1024) void scan_kernel(const int* __restrict__ deg, float* __restrict__ dis,
                                                    int* __restrict__ row_ptr, int* __restrict__ cursor,
                                                    unsigned int* __restrict__ csr_pack) {
    __shared__ int part[1024];
    int t = threadIdx.x;
    const int CH = NN / 1024;   // 32
    int base = t * CH;
    int sum = 0;
    for (int i = 0; i < CH; ++i) {
        int d = deg[base + i];
        dis[base + i] = rsqrtf((float)d);
        sum += d;               // self + in-degree
    }
    part[t] = sum;
    __syncthreads();
    for (int off = 1; off < 1024; off <<= 1) {
        int v = (t >= off) ? part[t - off] : 0;
        __syncthreads();
        part[t] += v;
        __syncthreads();
    }
    int excl = (t == 0) ? 0 : part[t - 1];
    for (int i = 0; i < CH; ++i) {
        int node = base + i;
        int d = deg[node];
        row_ptr[node] = excl;
        // self edge: weight = dis^2 = 1/deg exactly
        csr_pack[excl] = ((unsigned int)f2bf(1.0f / (float)d) << 16) | (unsigned int)node;
        cursor[node] = excl + 1;
        excl += d;
    }
    if (t == 1023) row_ptr[NN] = part[1023];
}

__global__ __launch_bounds__(256) void fill_csr(const int* __restrict__ src, const int* __restrict__ dst,
                                                const float* __restrict__ dis,
                                                int* __restrict__ cursor, unsigned int* __restrict__ csr_pack) {
    int e = blockIdx.x * 256 + threadIdx.x;
    if (e < NE) {
        int d = dst[e];
        int s = src[e];
        int pos = atomicAdd(&cursor[d], 1);
        csr_pack[pos] = ((unsigned int)f2bf(dis[s] * dis[d]) << 16) | (unsigned int)s;
    }
}

__global__ __launch_bounds__(128) void doc_attn(const float* __restrict__ attn, float* __restrict__ dm) {
    int d = blockIdx.x;
    int t = threadIdx.x;
    float v = attn[d * NPD + t];
    #pragma unroll
    for (int off = 32; off >= 1; off >>= 1) v += __shfl_down(v, off);
    __shared__ float sm[2];
    if ((t & 63) == 0) sm[t >> 6] = v;
    __syncthreads();
    if (t == 0) dm[d] = (sm[0] + sm[1]) * (1.0f / (float)NPD);
}

// ---------------------------------------------------------------------------
// conversions
// ---------------------------------------------------------------------------
__global__ __launch_bounds__(256) void cvt_x(const float* __restrict__ x, unsigned short* __restrict__ xb) {
    int i = blockIdx.x * 256 + threadIdx.x;   // per 4 elements
    float4 v = ((const float4*)x)[i];
    ushort4 o;
    o.x = f2bf(v.x); o.y = f2bf(v.y); o.z = f2bf(v.z); o.w = f2bf(v.w);
    ((ushort4*)xb)[i] = o;
}

// all weight transposes+casts in one kernel (grid = 868352/256 = 3392)
__global__ __launch_bounds__(256) void cvt_all(const float* __restrict__ Wi, const float* __restrict__ Wh,
                                               const float* __restrict__ Wo, const float* __restrict__ Wf1,
                                               const float* __restrict__ Wf2,
                                               unsigned short* __restrict__ Ti, unsigned short* __restrict__ Th,
                                               unsigned short* __restrict__ To, unsigned short* __restrict__ Tf1,
                                               unsigned short* __restrict__ Tf2) {
    int idx = blockIdx.x * 256 + threadIdx.x;
    if (idx < 65536) {                      // W_in [128 x 512]
        int k = idx >> 9, n = idx & 511;
        Ti[(size_t)n * FIN + k] = f2bf(Wi[idx]);
        return;
    }
    idx -= 65536;
    if (idx < 262144) {                     // W_hid [512 x 512]
        int k = idx >> 9, n = idx & 511;
        Th[(size_t)n * DD + k] = f2bf(Wh[idx]);
        return;
    }
    idx -= 262144;
    if (idx < 262144) {                     // W_out
        int k = idx >> 9, n = idx & 511;
        To[(size_t)n * DD + k] = f2bf(Wo[idx]);
        return;
    }
    idx -= 262144;
    if (idx < 262144) {                     // W_fc1
        int k = idx >> 9, n = idx & 511;
        Tf1[(size_t)n * DD + k] = f2bf(Wf1[idx]);
        return;
    }
    idx -= 262144;
    if (idx < 16384) {                      // W_fc2 [512 x 32]
        int k = idx >> 5, n = idx & 31;
        Tf2[(size_t)n * DD + k] = f2bf(Wf2[idx]);
    }
}

// ---------------------------------------------------------------------------
// MFMA bf16 GEMM: C[MxN] = A[MxK] @ Bt[NxK]^T (optional fused bias+tanh).
// 128x128 tile, BK=64, 4 waves, wave tile 64x64 (4x4 16x16x32 MFMA).
// XOR-swizzled LDS: row r's k-segment s (16 B) lives at r*128B + (s^(r&7))*16B.
// Staging folds the swizzle into the global source address (LDS dest stays
// contiguous as global_load_lds requires); fragment reads apply the same XOR.
// Result: quad's 16 lanes spread over all 8 bank groups (2-way = free) instead
// of 16-way same-bank conflicts (was 4.2M SQ_LDS_BANK_CONFLICT / dispatch).
// ---------------------------------------------------------------------------
template<bool FUSE>
__global__ __launch_bounds__(256) void mfma_gemm(const unsigned short* __restrict__ A,
                                                 const unsigned short* __restrict__ Bt,
                                                 const float* __restrict__ bias,
                                                 unsigned short* __restrict__ C,
                                                 int M, int N, int K) {
    __shared__ __align__(16) unsigned short As[128 * 64];
    __shared__ __align__(16) unsigned short Bs[128 * 64];
    int tid  = threadIdx.x;
    int lane = tid & 63;
    int wave = tid >> 6;
    int m0 = blockIdx.y * 128;
    int n0 = blockIdx.x * 128;
    int wm = (wave >> 1) * 64;
    int wn = (wave & 1) * 64;

    f32x4 zero = {0.f, 0.f, 0.f, 0.f};
    f32x4 acc[4][4];
    #pragma unroll
    for (int mi = 0; mi < 4; ++mi)
        #pragma unroll
        for (int ni = 0; ni < 4; ++ni) acc[mi][ni] = zero;

    int srow = tid >> 3;                          // 0..31: row within 32-row group
    int scol = (((tid & 7) ^ (srow & 7))) * 8;    // XOR-swizzled k-segment
    const unsigned short* abase = A  + (size_t)(m0 + srow) * K + scol;
    const unsigned short* bbase = Bt + (size_t)(n0 + srow) * K + scol;

    for (int k0 = 0; k0 < K; k0 += 64) {
        __syncthreads();
        #pragma unroll
        for (int i = 0; i < 4; ++i) {
            gl2lds16(abase + (size_t)i * 32 * K + k0, As + (size_t)(wave * 64 + i * 256) * 8);
            gl2lds16(bbase + (size_t)i * 32 * K + k0, Bs + (size_t)(wave * 64 + i * 256) * 8);
        }
        __syncthreads();
        #pragma unroll
        for (int ks = 0; ks < 2; ++ks) {
            int rr = lane & 15;
            int q  = lane >> 4;
            int swz = ((ks * 4 + q) ^ (rr & 7)) * 8;   // matches staging swizzle
            s16x8 af[4], bfr[4];
            #pragma unroll
            for (int mi = 0; mi < 4; ++mi)
                af[mi] = *(const s16x8*)(As + (size_t)(wm + mi * 16 + rr) * 64 + swz);
            #pragma unroll
            for (int ni = 0; ni < 4; ++ni)
                bfr[ni] = *(const s16x8*)(Bs + (size_t)(wn + ni * 16 + rr) * 64 + swz);
            #pragma unroll
            for (int mi = 0; mi < 4; ++mi)
                #pragma unroll
                for (int ni = 0; ni < 4; ++ni)
                    acc[mi][ni] = __builtin_amdgcn_mfma_f32_16x16x32_bf16(af[mi], bfr[ni], acc[mi][ni], 0, 0, 0);
        }
    }

    // epilogue: C/D layout col = lane&15, row = (lane>>4)*4 + reg
    int col = lane & 15;
    int rb  = (lane >> 4) * 4;
    #pragma unroll
    for (int ni = 0; ni < 4; ++ni) {
        int n = n0 + wn + ni * 16 + col;
        float bv = 0.f;
        if (FUSE) bv = bias[n];
        #pragma unroll
        for (int mi = 0; mi < 4; ++mi) {
            size_t base = (size_t)(m0 + wm + mi * 16 + rb) * N + n;
            #pragma unroll
            for (int r = 0; r < 4; ++r) {
                float v = acc[mi][ni][r];
                if (FUSE) v = tanhf(v + bv);
                C[base + (size_t)r * N] = f2bf(v);
            }
        }
    }
}

// ---------------------------------------------------------------------------
// 512-wide aggregation (R5 winner): one wave per node, lane = 8 cols (16 B
// coalesced row-gathers), uniform edge loop (self-edge in CSR), clamped
// 4-deep prefetch. out[n] = tanh(sum_e w_e * hw[src_e] + b)
// ---------------------------------------------------------------------------
__global__ __launch_bounds__(256) void agg512(const unsigned short* __restrict__ hw,
                                              const int* __restrict__ row_ptr,
                                              const unsigned int* __restrict__ csr_pack,
                                              const float* __restrict__ bias,
                                              unsigned short* __restrict__ out) {
    int n = blockIdx.x * 4 + (threadIdx.x >> 6);
    int lane = threadIdx.x & 63;
    int cb = lane * 8;
    const unsigned short* tab = hw + cb;
    float acc[8] = {};
    int beg = row_ptr[n], end = row_ptr[n + 1];
    for (int e = beg; e < end; e += 4) {
        int e1 = (e + 1 < end) ? e + 1 : e;
        int e2 = (e + 2 < end) ? e + 2 : e;
        int e3 = (e + 3 < end) ? e + 3 : e;
        unsigned int p0 = csr_pack[e];
        unsigned int p1 = csr_pack[e1];
        unsigned int p2 = csr_pack[e2];
        unsigned int p3 = csr_pack[e3];
        s16x8 u0 = *(const s16x8*)(tab + (size_t)(p0 & 0xffffu) * DD);
        s16x8 u1 = *(const s16x8*)(tab + (size_t)(p1 & 0xffffu) * DD);
        s16x8 u2 = *(const s16x8*)(tab + (size_t)(p2 & 0xffffu) * DD);
        s16x8 u3 = *(const s16x8*)(tab + (size_t)(p3 & 0xffffu) * DD);
        float w0 = bf2f(p0 >> 16);
        float w1 = (e + 1 < end) ? bf2f(p1 >> 16) : 0.f;
        float w2 = (e + 2 < end) ? bf2f(p2 >> 16) : 0.f;
        float w3 = (e + 3 < end) ? bf2f(p3 >> 16) : 0.f;
        #pragma unroll
        for (int j = 0; j < 8; ++j) acc[j] += w0 * bf2f((unsigned short)u0[j]);
        #pragma unroll
        for (int j = 0; j < 8; ++j) acc[j] += w1 * bf2f((unsigned short)u1[j]);
        #pragma unroll
        for (int j = 0; j < 8; ++j) acc[j] += w2 * bf2f((unsigned short)u2[j]);
        #pragma unroll
        for (int j = 0; j < 8; ++j) acc[j] += w3 * bf2f((unsigned short)u3[j]);
    }
    s16x8 o;
    #pragma unroll
    for (int j = 0; j < 8; ++j)
        o[j] = (short)f2bf(tanhf(acc[j] + bias[cb + j]));
    *(s16x8*)(out + (size_t)n * DD + cb) = o;
}

// ---------------------------------------------------------------------------
// 128-wide pre-aggregation of x (R5 winner): lane = 2 cols (u32 gathers)
// ---------------------------------------------------------------------------
__global__ __launch_bounds__(256) void agg128(const unsigned short* __restrict__ xb,
                                              const int* __restrict__ row_ptr,
                                              const unsigned int* __restrict__ csr_pack,
                                              unsigned short* __restrict__ xagg) {
    int n = blockIdx.x * 4 + (threadIdx.x >> 6);
    int lane = threadIdx.x & 63;
    int cb = lane * 2;
    const unsigned short* tab = xb + cb;
    float a0 = 0.f, a1 = 0.f;
    int beg = row_ptr[n], end = row_ptr[n + 1];
    for (int e = beg; e < end; e += 4) {
        int e1 = (e + 1 < end) ? e + 1 : e;
        int e2 = (e + 2 < end) ? e + 2 : e;
        int e3 = (e + 3 < end) ? e + 3 : e;
        unsigned int p0 = csr_pack[e];
        unsigned int p1 = csr_pack[e1];
        unsigned int p2 = csr_pack[e2];
        unsigned int p3 = csr_pack[e3];
        unsigned int u0 = *(const unsigned int*)(tab + (size_t)(p0 & 0xffffu) * FIN);
        unsigned int u1 = *(const unsigned int*)(tab + (size_t)(p1 & 0xffffu) * FIN);
        unsigned int u2 = *(const unsigned int*)(tab + (size_t)(p2 & 0xffffu) * FIN);
        unsigned int u3 = *(const unsigned int*)(tab + (size_t)(p3 & 0xffffu) * FIN);
        float w0 = bf2f(p0 >> 16);
        float w1 = (e + 1 < end) ? bf2f(p1 >> 16) : 0.f;
        float w2 = (e + 2 < end) ? bf2f(p2 >> 16) : 0.f;
        float w3 = (e + 3 < end) ? bf2f(p3 >> 16) : 0.f;
        a0 += w0 * bf2f(u0 & 0xffffu); a1 += w0 * bf2f(u0 >> 16);
        a0 += w1 * bf2f(u1 & 0xffffu); a1 += w1 * bf2f(u1 >> 16);
        a0 += w2 * bf2f(u2 & 0xffffu); a1 += w2 * bf2f(u2 >> 16);
        a0 += w3 * bf2f(u3 & 0xffffu); a1 += w3 * bf2f(u3 >> 16);
    }
    unsigned int o = (unsigned int)f2bf(a0) | ((unsigned int)f2bf(a1) << 16);
    *(unsigned int*)(xagg + (size_t)n * FIN + cb) = o;
}

// ---------------------------------------------------------------------------
// fused fc2+fc3+pool: one block per doc (128 nodes), MFMA 128x32, K=512
// ---------------------------------------------------------------------------
__global__ __launch_bounds__(256) void fc23_pool(const unsigned short* __restrict__ H,
                                                 const unsigned short* __restrict__ W2t,
                                                 const float* __restrict__ b2,
                                                 const float* __restrict__ W3,
                                                 const float* __restrict__ b3,
                                                 float* __restrict__ util) {
    __shared__ __align__(16) unsigned short As[128 * 64];
    __shared__ __align__(16) unsigned short Bs[32 * 64];
    __shared__ float red[4];
    int d = blockIdx.x;
    int tid = threadIdx.x;
    int lane = tid & 63;
    int wave = tid >> 6;
    const unsigned short* A = H + (size_t)d * NPD * DD;

    f32x4 zero = {0.f, 0.f, 0.f, 0.f};
    f32x4 acc[2][2];
    #pragma unroll
    for (int mi = 0; mi < 2; ++mi)
        #pragma unroll
        for (int ni = 0; ni < 2; ++ni) acc[mi][ni] = zero;

    int srow = tid >> 3;
    int scol = (tid & 7) * 8;
    for (int k0 = 0; k0 < DD; k0 += 64) {
        __syncthreads();
        #pragma unroll
        for (int i = 0; i < 4; ++i)
            gl2lds16(A + (size_t)(srow + i * 32) * DD + k0 + scol,
                     As + (size_t)(wave * 64 + i * 256) * 8);
        gl2lds16(W2t + (size_t)srow * DD + k0 + scol, Bs + (size_t)(wave * 64) * 8);
        __syncthreads();
        #pragma unroll
        for (int ks = 0; ks < 2; ++ks) {
            int kk = ks * 32 + (lane >> 4) * 8;
            s16x8 af[2], bfr[2];
            #pragma unroll
            for (int mi = 0; mi < 2; ++mi)
                af[mi] = *(const s16x8*)(As + (size_t)(wave * 32 + mi * 16 + (lane & 15)) * 64 + kk);
            #pragma unroll
            for (int ni = 0; ni < 2; ++ni)
                bfr[ni] = *(const s16x8*)(Bs + (size_t)(ni * 16 + (lane & 15)) * 64 + kk);
            #pragma unroll
            for (int mi = 0; mi < 2; ++mi)
                #pragma unroll
                for (int ni = 0; ni < 2; ++ni)
                    acc[mi][ni] = __builtin_amdgcn_mfma_f32_16x16x32_bf16(af[mi], bfr[ni], acc[mi][ni], 0, 0, 0);
        }
    }

    int col = lane & 15;
    float part = 0.f;
    #pragma unroll
    for (int ni = 0; ni < 2; ++ni) {
        int j = ni * 16 + col;
        float b2v = b2[j];
        float w3v = W3[j];
        #pragma unroll
        for (int mi = 0; mi < 2; ++mi)
            #pragma unroll
            for (int r = 0; r < 4; ++r)
                part += tanhf(acc[mi][ni][r] + b2v) * w3v;
    }
    #pragma unroll
    for (int off = 32; off >= 1; off >>= 1) part += __shfl_down(part, off);
    if (lane == 0) red[wave] = part;
    __syncthreads();
    if (tid == 0) util[d] = (red[0] + red[1] + red[2] + red[3]) * (1.0f / (float)NPD) + b3[0];
}

__global__ __launch_bounds__(256) void final_kernel(const float* __restrict__ util, const float* __restrict__ dm,
                                                    const int* __restrict__ ia, const int* __restrict__ ib,
                                                    float* __restrict__ out) {
    int i = threadIdx.x;
    if (i < NDOCS) {
        float diff = util[ib[i]] - util[ia[i]];
        float a = dm[i ^ 1];
        out[i] = 1.0f / (1.0f + expf(-diff * a));
    }
}

// ---------------------------------------------------------------------------
// launch
// ---------------------------------------------------------------------------
extern "C" void kernel_launch(void* const* d_in, const int* in_sizes, int n_in,
                              void* d_out, int out_size, void* d_ws, size_t ws_size,
                              hipStream_t stream) {
    const float* x      = (const float*)d_in[0];
    const int*   ei     = (const int*)d_in[1];
    const int*   e_src  = ei;
    const int*   e_dst  = ei + NE;
    const float* attn   = (const float*)d_in[4];
    const int*   idx_a  = (const int*)d_in[5];
    const int*   idx_b  = (const int*)d_in[6];
    const float* W_in   = (const float*)d_in[7];
    const float* b_in   = (const float*)d_in[8];
    const float* W_hid  = (const float*)d_in[9];
    const float* b_hid  = (const float*)d_in[10];
    const float* W_out  = (const float*)d_in[11];
    const float* b_out  = (const float*)d_in[12];
    const float* W_fc1  = (const float*)d_in[13];
    const float* b_fc1  = (const float*)d_in[14];
    const float* W_fc2  = (const float*)d_in[15];
    const float* b_fc2  = (const float*)d_in[16];
    const float* W_fc3  = (const float*)d_in[17];
    const float* b_fc3  = (const float*)d_in[18];
    float* out = (float*)d_out;

    // workspace carve-up (16B-aligned by construction)
    char* p = (char*)d_ws;
    unsigned short* hw_bf  = (unsigned short*)p; p += (size_t)NN * DD * 2;   // 32 MB (also hosts xagg)
    unsigned short* h_bf   = (unsigned short*)p; p += (size_t)NN * DD * 2;   // 32 MB
    unsigned short* xb     = (unsigned short*)p; p += (size_t)NN * FIN * 2;  // 8 MB
    unsigned short* Wt_in  = (unsigned short*)p; p += (size_t)DD * FIN * 2;
    unsigned short* Wt_hid = (unsigned short*)p; p += (size_t)DD * DD * 2;
    unsigned short* Wt_out = (unsigned short*)p; p += (size_t)DD * DD * 2;
    unsigned short* Wt_fc1 = (unsigned short*)p; p += (size_t)DD * DD * 2;
    unsigned short* W2t    = (unsigned short*)p; p += (size_t)32 * DD * 2;
    int*   degi     = (int*)p;   p += (size_t)NN * 4;
    float* dis      = (float*)p; p += (size_t)NN * 4;
    float* dm       = (float*)p; p += (size_t)NDOCS * 4;
    float* util     = (float*)p; p += (size_t)NDOCS * 4;
    int*   row_ptr  = (int*)p;   p += (size_t)(NN + 1) * 4 + 12;
    int*   cursor   = (int*)p;   p += (size_t)NN * 4;
    unsigned int* csr_pack = (unsigned int*)p;   p += (size_t)(NE + NN) * 4;
    unsigned short* xagg = hw_bf;   // 8 MB, aliases hw_bf (free before layer-1 GEMM writes h_bf)

    // graph structure
    init_deg<<<NN / 256, 256, 0, stream>>>(degi);
    count_deg<<<NE / 256, 256, 0, stream>>>(e_dst, degi);
    scan_kernel<<<1, 1024, 0, stream>>>(degi, dis, row_ptr, cursor, csr_pack);
    fill_csr<<<NE / 256, 256, 0, stream>>>(e_src, e_dst, dis, cursor, csr_pack);
    doc_attn<<<NDOCS, 128, 0, stream>>>(attn, dm);

    // dtype prep
    cvt_x<<<(NN * FIN / 4) / 256, 256, 0, stream>>>(x, xb);
    cvt_all<<<3392, 256, 0, stream>>>(W_in, W_hid, W_out, W_fc1, W_fc2,
                                      Wt_in, Wt_hid, Wt_out, Wt_fc1, W2t);

    dim3 gg(DD / 128, NN / 128);   // (4, 256)

    // layer 1: aggregate x first (A_norm x) @ W_in, fused bias+tanh
    agg128<<<NN / 4, 256, 0, stream>>>(xb, row_ptr, csr_pack, xagg);
    mfma_gemm<true><<<gg, 256, 0, stream>>>(xagg, Wt_in, b_in, h_bf, NN, DD, FIN);
    // layer 2
    mfma_gemm<false><<<gg, 256, 0, stream>>>(h_bf, Wt_hid, nullptr, hw_bf, NN, DD, DD);
    agg512<<<NN / 4, 256, 0, stream>>>(hw_bf, row_ptr, csr_pack, b_hid, h_bf);
    // layer 3
    mfma_gemm<false><<<gg, 256, 0, stream>>>(h_bf, Wt_hid, nullptr, hw_bf, NN, DD, DD);
    agg512<<<NN / 4, 256, 0, stream>>>(hw_bf, row_ptr, csr_pack, b_hid, h_bf);
    // layer 4
    mfma_gemm<false><<<gg, 256, 0, stream>>>(h_bf, Wt_out, nullptr, hw_bf, NN, DD, DD);
    agg512<<<NN / 4, 256, 0, stream>>>(hw_bf, row_ptr, csr_pack, b_out, h_bf);
    // fc1 (fused bias+tanh)
    mfma_gemm<true><<<gg, 256, 0, stream>>>(h_bf, Wt_fc1, b_fc1, hw_bf, NN, DD, DD);
    // fc2+fc3+pool fused
    fc23_pool<<<NDOCS, 256, 0, stream>>>(hw_bf, W2t, b_fc2, W_fc3, b_fc3, util);
    // readout
    final_kernel<<<1, 256, 0, stream>>>(util, dm, idx_a, idx_b, out);
}